// Round 3
// baseline (4050.526 us; speedup 1.0000x reference)
//
#include <hip/hip_runtime.h>

#define HID 64
#define IN_DIM 128
#define TAU_DIM 8
#define SCAN_B 1024

// ---------------- CSR build ----------------
// All index inputs are bounds-guarded: malformed edge data must produce a
// wrong answer (validation failure), never a device memory fault.

__global__ void zero_int_kernel(int* __restrict__ p, int n) {
    int i = blockIdx.x * blockDim.x + threadIdx.x;
    if (i < n) p[i] = 0;
}

__global__ void count_deg_kernel(const int* __restrict__ row, int* __restrict__ deg,
                                 int e, int n) {
    int i = blockIdx.x * blockDim.x + threadIdx.x;
    if (i < e) {
        int r = row[i];
        if ((unsigned)r < (unsigned)n) atomicAdd(&deg[r], 1);
    }
}

__global__ void block_sum_kernel(const int* __restrict__ deg, int* __restrict__ blk, int n) {
    __shared__ int s[SCAN_B];
    int i = blockIdx.x * SCAN_B + threadIdx.x;
    s[threadIdx.x] = (i < n) ? deg[i] : 0;
    __syncthreads();
    for (int off = SCAN_B / 2; off > 0; off >>= 1) {
        if (threadIdx.x < off) s[threadIdx.x] += s[threadIdx.x + off];
        __syncthreads();
    }
    if (threadIdx.x == 0) blk[blockIdx.x] = s[0];
}

__global__ void scan_blk_kernel(int* __restrict__ blk, int nb) {
    __shared__ int s[SCAN_B];
    int v = (threadIdx.x < nb) ? blk[threadIdx.x] : 0;
    s[threadIdx.x] = v;
    __syncthreads();
    for (int off = 1; off < SCAN_B; off <<= 1) {
        int t = (threadIdx.x >= off) ? s[threadIdx.x - off] : 0;
        __syncthreads();
        s[threadIdx.x] += t;
        __syncthreads();
    }
    if (threadIdx.x < nb) blk[threadIdx.x] = s[threadIdx.x] - v;  // exclusive
}

__global__ void scan_final_kernel(const int* __restrict__ deg, const int* __restrict__ blk,
                                  int* __restrict__ row_start, int* __restrict__ cursor, int n) {
    __shared__ int s[SCAN_B];
    int i = blockIdx.x * SCAN_B + threadIdx.x;
    int v = (i < n) ? deg[i] : 0;
    s[threadIdx.x] = v;
    __syncthreads();
    for (int off = 1; off < SCAN_B; off <<= 1) {
        int t = (threadIdx.x >= off) ? s[threadIdx.x - off] : 0;
        __syncthreads();
        s[threadIdx.x] += t;
        __syncthreads();
    }
    if (i < n) {
        int excl = s[threadIdx.x] - v + blk[blockIdx.x];
        row_start[i] = excl;
        cursor[i]    = excl;
    }
}

__global__ void fill_csr_kernel(const int* __restrict__ row, const int* __restrict__ col,
                                int* __restrict__ cursor, int* __restrict__ cols,
                                int e, int n) {
    int i = blockIdx.x * blockDim.x + threadIdx.x;
    if (i < e) {
        int r = row[i];
        if ((unsigned)r < (unsigned)n) {
            int c = col[i];
            if ((unsigned)c >= (unsigned)n) c = 0;  // never store an OOB index
            int p = atomicAdd(&cursor[r], 1);
            cols[p] = c;
        }
    }
}

// ---------------- init: h0 = relu(x@W_in.T+b), tau = mean(sigmoid(relu(x@W_t1.T+b)@W_t2.T+b)) ----------------

__global__ __launch_bounds__(256) void init_kernel(
    const float* __restrict__ x,
    const float* __restrict__ W_in, const float* __restrict__ b_in,
    const float* __restrict__ W_t1, const float* __restrict__ b_t1,
    const float* __restrict__ W_t2, const float* __restrict__ b_t2,
    float* __restrict__ h, float* __restrict__ tau, int n) {
    int v = blockIdx.x * blockDim.x + threadIdx.x;
    if (v >= n) return;

    float4 xr[32];
    const float4* xp = (const float4*)(x + (size_t)v * IN_DIM);
#pragma unroll
    for (int k = 0; k < 32; k++) xr[k] = xp[k];

    float* hv = h + (size_t)v * HID;
#pragma unroll 1
    for (int jg = 0; jg < 16; jg++) {
        int j = jg * 4;
        float a0 = b_in[j], a1 = b_in[j + 1], a2 = b_in[j + 2], a3 = b_in[j + 3];
        const float4* w0 = (const float4*)(W_in + (size_t)(j + 0) * IN_DIM);
        const float4* w1 = (const float4*)(W_in + (size_t)(j + 1) * IN_DIM);
        const float4* w2 = (const float4*)(W_in + (size_t)(j + 2) * IN_DIM);
        const float4* w3 = (const float4*)(W_in + (size_t)(j + 3) * IN_DIM);
#pragma unroll
        for (int k = 0; k < 32; k++) {
            float4 xv = xr[k];
            float4 wa = w0[k], wb = w1[k], wc = w2[k], wd = w3[k];
            a0 += wa.x * xv.x + wa.y * xv.y + wa.z * xv.z + wa.w * xv.w;
            a1 += wb.x * xv.x + wb.y * xv.y + wb.z * xv.z + wb.w * xv.w;
            a2 += wc.x * xv.x + wc.y * xv.y + wc.z * xv.z + wc.w * xv.w;
            a3 += wd.x * xv.x + wd.y * xv.y + wd.z * xv.z + wd.w * xv.w;
        }
        *(float4*)(hv + j) = make_float4(fmaxf(a0, 0.f), fmaxf(a1, 0.f),
                                         fmaxf(a2, 0.f), fmaxf(a3, 0.f));
    }

    float t_acc[TAU_DIM];
#pragma unroll
    for (int m = 0; m < TAU_DIM; m++) t_acc[m] = b_t2[m];

#pragma unroll 1
    for (int jg = 0; jg < 16; jg++) {
        int j = jg * 4;
        float a0 = b_t1[j], a1 = b_t1[j + 1], a2 = b_t1[j + 2], a3 = b_t1[j + 3];
        const float4* w0 = (const float4*)(W_t1 + (size_t)(j + 0) * IN_DIM);
        const float4* w1 = (const float4*)(W_t1 + (size_t)(j + 1) * IN_DIM);
        const float4* w2 = (const float4*)(W_t1 + (size_t)(j + 2) * IN_DIM);
        const float4* w3 = (const float4*)(W_t1 + (size_t)(j + 3) * IN_DIM);
#pragma unroll
        for (int k = 0; k < 32; k++) {
            float4 xv = xr[k];
            float4 wa = w0[k], wb = w1[k], wc = w2[k], wd = w3[k];
            a0 += wa.x * xv.x + wa.y * xv.y + wa.z * xv.z + wa.w * xv.w;
            a1 += wb.x * xv.x + wb.y * xv.y + wb.z * xv.z + wb.w * xv.w;
            a2 += wc.x * xv.x + wc.y * xv.y + wc.z * xv.z + wc.w * xv.w;
            a3 += wd.x * xv.x + wd.y * xv.y + wd.z * xv.z + wd.w * xv.w;
        }
        a0 = fmaxf(a0, 0.f); a1 = fmaxf(a1, 0.f); a2 = fmaxf(a2, 0.f); a3 = fmaxf(a3, 0.f);
#pragma unroll
        for (int m = 0; m < TAU_DIM; m++) {
            t_acc[m] += W_t2[(size_t)m * HID + j]     * a0
                      + W_t2[(size_t)m * HID + j + 1] * a1
                      + W_t2[(size_t)m * HID + j + 2] * a2
                      + W_t2[(size_t)m * HID + j + 3] * a3;
        }
    }
    float tsum = 0.f;
#pragma unroll
    for (int m = 0; m < TAU_DIM; m++) tsum += 1.f / (1.f + expf(-t_acc[m]));
    tau[v] = tsum * (1.f / TAU_DIM);
}

// ---------------- aggregate: agg[v] = tau[v] * sum_e |h[v]-h[col[e]]| ----------------
// 16 lanes per node, float4 per lane (64 comps). CSR, no atomics.
// Edge loop 2-way unrolled: two independent cols->h dependent chains in flight.

__global__ __launch_bounds__(256) void aggregate_kernel(
    const float* __restrict__ h, const float* __restrict__ tau,
    const int* __restrict__ row_start, const int* __restrict__ deg,
    const int* __restrict__ cols, float* __restrict__ agg, int n) {
    int t = blockIdx.x * blockDim.x + threadIdx.x;
    int v = t >> 4;
    if (v >= n) return;
    int c4 = (t & 15) * 4;

    float4 hv = *(const float4*)(h + (size_t)v * HID + c4);
    float4 s0 = make_float4(0.f, 0.f, 0.f, 0.f);
    float4 s1 = make_float4(0.f, 0.f, 0.f, 0.f);
    int st = row_start[v];
    int d  = deg[v];
    int i = 0;
    for (; i + 1 < d; i += 2) {
        int c0 = cols[st + i];
        int c1 = cols[st + i + 1];
        float4 hc0 = *(const float4*)(h + (size_t)c0 * HID + c4);
        float4 hc1 = *(const float4*)(h + (size_t)c1 * HID + c4);
        s0.x += fabsf(hv.x - hc0.x);
        s0.y += fabsf(hv.y - hc0.y);
        s0.z += fabsf(hv.z - hc0.z);
        s0.w += fabsf(hv.w - hc0.w);
        s1.x += fabsf(hv.x - hc1.x);
        s1.y += fabsf(hv.y - hc1.y);
        s1.z += fabsf(hv.z - hc1.z);
        s1.w += fabsf(hv.w - hc1.w);
    }
    if (i < d) {
        int c = cols[st + i];
        float4 hc = *(const float4*)(h + (size_t)c * HID + c4);
        s0.x += fabsf(hv.x - hc.x);
        s0.y += fabsf(hv.y - hc.y);
        s0.z += fabsf(hv.z - hc.z);
        s0.w += fabsf(hv.w - hc.w);
    }
    float tv = tau[v];
    *(float4*)(agg + (size_t)v * HID + c4) =
        make_float4((s0.x + s1.x) * tv, (s0.y + s1.y) * tv,
                    (s0.z + s1.z) * tv, (s0.w + s1.w) * tv);
}

// ---------------- GRU cell (in-place h update) ----------------

__global__ __launch_bounds__(256) void gru_kernel(
    const float* __restrict__ agg, float* __restrict__ h,
    const float* __restrict__ W_ih, const float* __restrict__ b_ih,
    const float* __restrict__ W_hh, const float* __restrict__ b_hh, int n) {
    int v = blockIdx.x * blockDim.x + threadIdx.x;
    if (v >= n) return;

    float4 a4[16], h4[16];
    const float4* ap = (const float4*)(agg + (size_t)v * HID);
    float* hrow = h + (size_t)v * HID;
    const float4* hp = (const float4*)hrow;
#pragma unroll
    for (int k = 0; k < 16; k++) { a4[k] = ap[k]; h4[k] = hp[k]; }

#pragma unroll 1
    for (int jg = 0; jg < 16; jg++) {
        // old-h for this output group: reload from global (L1 hit) to avoid
        // dynamic register-array indexing (scratch spill, rule #20).
        float4 hold = *(const float4*)(hrow + jg * 4);
        float hops[4] = {hold.x, hold.y, hold.z, hold.w};
        float outv[4];
#pragma unroll
        for (int jj = 0; jj < 4; jj++) {
            int j = jg * 4 + jj;
            float ir = b_ih[j], iz = b_ih[HID + j], in_ = b_ih[2 * HID + j];
            float hr = b_hh[j], hz = b_hh[HID + j], hn  = b_hh[2 * HID + j];
            const float4* wir = (const float4*)(W_ih + (size_t)j * HID);
            const float4* wiz = (const float4*)(W_ih + (size_t)(HID + j) * HID);
            const float4* win = (const float4*)(W_ih + (size_t)(2 * HID + j) * HID);
            const float4* whr = (const float4*)(W_hh + (size_t)j * HID);
            const float4* whz = (const float4*)(W_hh + (size_t)(HID + j) * HID);
            const float4* whn = (const float4*)(W_hh + (size_t)(2 * HID + j) * HID);
#pragma unroll
            for (int k = 0; k < 16; k++) {
                float4 av = a4[k], hv = h4[k];
                float4 w;
                w = wir[k]; ir  += w.x * av.x + w.y * av.y + w.z * av.z + w.w * av.w;
                w = wiz[k]; iz  += w.x * av.x + w.y * av.y + w.z * av.z + w.w * av.w;
                w = win[k]; in_ += w.x * av.x + w.y * av.y + w.z * av.z + w.w * av.w;
                w = whr[k]; hr  += w.x * hv.x + w.y * hv.y + w.z * hv.z + w.w * hv.w;
                w = whz[k]; hz  += w.x * hv.x + w.y * hv.y + w.z * hv.z + w.w * hv.w;
                w = whn[k]; hn  += w.x * hv.x + w.y * hv.y + w.z * hv.z + w.w * hv.w;
            }
            float r  = 1.f / (1.f + expf(-(ir + hr)));
            float z  = 1.f / (1.f + expf(-(iz + hz)));
            float nn = tanhf(in_ + r * hn);
            outv[jj] = (1.f - z) * nn + z * hops[jj];
        }
        *(float4*)(hrow + jg * 4) = make_float4(outv[0], outv[1], outv[2], outv[3]);
    }
}

// ---------------- output projection ----------------

__global__ __launch_bounds__(256) void out_kernel(
    const float* __restrict__ h, const float* __restrict__ W_out,
    const float* __restrict__ b_out, float* __restrict__ out, int n) {
    int v = blockIdx.x * blockDim.x + threadIdx.x;
    if (v >= n) return;
    float4 h4[16];
    const float4* hp = (const float4*)(h + (size_t)v * HID);
#pragma unroll
    for (int k = 0; k < 16; k++) h4[k] = hp[k];
    float* orow = out + (size_t)v * HID;
#pragma unroll 1
    for (int jg = 0; jg < 16; jg++) {
        float acc[4];
#pragma unroll
        for (int jj = 0; jj < 4; jj++) {
            int j = jg * 4 + jj;
            float a = b_out[j];
            const float4* w = (const float4*)(W_out + (size_t)j * HID);
#pragma unroll
            for (int k = 0; k < 16; k++) {
                float4 wv = w[k], hv = h4[k];
                a += wv.x * hv.x + wv.y * hv.y + wv.z * hv.z + wv.w * hv.w;
            }
            acc[jj] = a;
        }
        *(float4*)(orow + jg * 4) = make_float4(acc[0], acc[1], acc[2], acc[3]);
    }
}

// ---------------- launch ----------------

extern "C" void kernel_launch(void* const* d_in, const int* in_sizes, int n_in,
                              void* d_out, int out_size, void* d_ws, size_t ws_size,
                              hipStream_t stream) {
    const float* x     = (const float*)d_in[0];
    const int*   ei    = (const int*)d_in[1];
    const float* W_in  = (const float*)d_in[2];
    const float* b_in  = (const float*)d_in[3];
    const float* W_t1  = (const float*)d_in[4];
    const float* b_t1  = (const float*)d_in[5];
    const float* W_t2  = (const float*)d_in[6];
    const float* b_t2  = (const float*)d_in[7];
    const float* W_ih  = (const float*)d_in[8];
    const float* b_ih  = (const float*)d_in[9];
    const float* W_hh  = (const float*)d_in[10];
    const float* b_hh  = (const float*)d_in[11];
    const float* W_out = (const float*)d_in[12];
    const float* b_out = (const float*)d_in[13];
    float* out = (float*)d_out;

    const int n = in_sizes[0] / IN_DIM;  // 100000
    const int e = in_sizes[1] / 2;       // 1000000
    const int* row = ei;
    const int* col = ei + e;

    char* ws = (char*)d_ws;
    float* h   = (float*)ws;  ws += (size_t)n * HID * sizeof(float);
    float* agg = (float*)ws;  ws += (size_t)n * HID * sizeof(float);
    float* tau = (float*)ws;  ws += (size_t)n * sizeof(float);
    int* deg       = (int*)ws;  ws += (size_t)n * sizeof(int);
    int* row_start = (int*)ws;  ws += (size_t)n * sizeof(int);
    int* cursor    = (int*)ws;  ws += (size_t)n * sizeof(int);
    int* blk       = (int*)ws;  ws += SCAN_B * sizeof(int);
    int* cols      = (int*)ws;  ws += (size_t)e * sizeof(int);

    const int nb = (n + SCAN_B - 1) / SCAN_B;

    zero_int_kernel<<<(n + 255) / 256, 256, 0, stream>>>(deg, n);
    count_deg_kernel<<<(e + 255) / 256, 256, 0, stream>>>(row, deg, e, n);
    block_sum_kernel<<<nb, SCAN_B, 0, stream>>>(deg, blk, n);
    scan_blk_kernel<<<1, SCAN_B, 0, stream>>>(blk, nb);
    scan_final_kernel<<<nb, SCAN_B, 0, stream>>>(deg, blk, row_start, cursor, n);
    fill_csr_kernel<<<(e + 255) / 256, 256, 0, stream>>>(row, col, cursor, cols, e, n);

    init_kernel<<<(n + 255) / 256, 256, 0, stream>>>(x, W_in, b_in, W_t1, b_t1,
                                                     W_t2, b_t2, h, tau, n);
    for (int it = 0; it < 5; ++it) {
        aggregate_kernel<<<((n * 16) + 255) / 256, 256, 0, stream>>>(
            h, tau, row_start, deg, cols, agg, n);
        gru_kernel<<<(n + 255) / 256, 256, 0, stream>>>(agg, h, W_ih, b_ih, W_hh, b_hh, n);
    }
    out_kernel<<<(n + 255) / 256, 256, 0, stream>>>(h, W_out, b_out, out, n);
}